// Round 1
// baseline (49.309 us; speedup 1.0000x reference)
//
#include <hip/hip_runtime.h>

#define NUM_BINS 10
#define NWAVES 4  // 256 threads / 64

__global__ __launch_bounds__(256) void count_res_hist(
    const float* __restrict__ res,
    const float* __restrict__ gt,
    int* __restrict__ out,
    int n4)  // number of float4 quads
{
    __shared__ int hist[NWAVES][2 * NUM_BINS];

    const int tid  = threadIdx.x;
    const int wave = tid >> 6;

    // Zero the per-wave sub-histograms (4*20 = 80 ints).
    if (tid < NWAVES * 2 * NUM_BINS) ((int*)hist)[tid] = 0;
    __syncthreads();

    const int idx    = blockIdx.x * blockDim.x + tid;
    const int stride = gridDim.x * blockDim.x;

    const float4* __restrict__ res4 = (const float4*)res;
    const float4* __restrict__ gt4  = (const float4*)gt;

    for (int i = idx; i < n4; i += stride) {
        float4 r = res4[i];
        float4 g = gt4[i];
        const float* rp = &r.x;
        const float* gp = &g.x;
        #pragma unroll
        for (int j = 0; j < 4; ++j) {
            float rv = rp[j];
            float gv = gp[j];
            // Match numpy: int32 truncation of float32 division by 0.1f, clipped.
            int b = (int)(rv / 0.1f);
            b = b < 0 ? 0 : (b > NUM_BINS - 1 ? NUM_BINS - 1 : b);
            // ano (gt > 0.5) -> counters [0,10); nor -> counters [10,20)
            int c = (gv > 0.5f) ? b : (NUM_BINS + b);
            atomicAdd(&hist[wave][c], 1);
        }
    }
    __syncthreads();

    // Reduce the 4 per-wave sub-histograms and add to global output.
    if (tid < 2 * NUM_BINS) {
        int s = hist[0][tid] + hist[1][tid] + hist[2][tid] + hist[3][tid];
        if (s) atomicAdd(&out[tid], s);
    }
}

extern "C" void kernel_launch(void* const* d_in, const int* in_sizes, int n_in,
                              void* d_out, int out_size, void* d_ws, size_t ws_size,
                              hipStream_t stream) {
    const float* res = (const float*)d_in[0];
    const float* gt  = (const float*)d_in[1];
    int* out = (int*)d_out;

    const int n  = in_sizes[0];      // 64*512*512 = 16,777,216 (divisible by 4)
    const int n4 = n >> 2;

    // Harness poisons d_out with 0xAA and never re-zeros between replays;
    // kernel accumulates with atomics, so zero it on-stream (capture-safe).
    hipMemsetAsync(d_out, 0, 2 * NUM_BINS * sizeof(int), stream);

    const int block = 256;
    int grid = (n4 + block - 1) / block;
    if (grid > 2048) grid = 2048;    // grid-stride the rest (G11)

    count_res_hist<<<grid, block, 0, stream>>>(res, gt, out, n4);
}